// Round 9
// baseline (484.297 us; speedup 1.0000x reference)
//
#include <hip/hip_runtime.h>
#include <hip/hip_bf16.h>

#define GRID_W 64
#define NPTS   4096
#define BATCH  8
#define DD     32
#define DIN    80
#define HID    128
#define SH_STRIDE 136              // ushort stride (17*16B) -> conflict-free b128
#define SQ_STRIDE 36               // f32 stride for LDS state rows
#define NBLK   512                 // one grid-row per block
#define NFULL  17                  // max full leapfrog steps for tf <= 4.0
#define NSTEP  34                  // fallback: half-steps
// ws layout: flags (512*64B) | fragment weights | double-buffered q/p state
#define OFF_F1Q 32768
#define OFF_F2Q (OFF_F1Q + 24*64*16)
#define OFF_F1P (OFF_F2Q + 8*64*16)
#define OFF_F2P (OFF_F1P + 24*64*16)
#define OFF_BUF0 (1 << 17)
#define BUFSZ   (BATCH * 64 * 64 * 64 * 4)      // 8 MB: [b][row][pt][q32|p32] f32
#define OFF_BUF1 (OFF_BUF0 + BUFSZ)

typedef __attribute__((ext_vector_type(8))) short short8;
typedef __attribute__((ext_vector_type(4))) float f32x4;
typedef unsigned long long u64;

__device__ __forceinline__ ushort f2bf(float v) {
    __hip_bfloat16 h = __float2bfloat16(v);
    return __builtin_bit_cast(ushort, h);
}
__device__ __forceinline__ uint packbf(float a, float b) {
    return (uint)f2bf(a) | ((uint)f2bf(b) << 16);
}
__device__ __forceinline__ short8 pack8(float4 a, float4 b) {
    union { uint u[4]; short8 s; } t;
    t.u[0] = packbf(a.x, a.y); t.u[1] = packbf(a.z, a.w);
    t.u[2] = packbf(b.x, b.y); t.u[3] = packbf(b.z, b.w);
    return t.s;
}
__device__ __forceinline__ float4 avg4(float4 u, float4 d, float4 l, float4 r) {
    float4 m;
    m.x = 0.25f * (u.x + d.x + l.x + r.x);
    m.y = 0.25f * (u.y + d.y + l.y + r.y);
    m.z = 0.25f * (u.z + d.z + l.z + r.z);
    m.w = 0.25f * (u.w + d.w + l.w + r.w);
    return m;
}
__device__ __forceinline__ float4 addf4(float4 a, float4 b) {
    float4 m; m.x = a.x + b.x; m.y = a.y + b.y; m.z = a.z + b.z; m.w = a.w + b.w;
    return m;
}

// System-scope (L3-coherent) 16B ld/st as 2x8B relaxed atomics. Proven r5-r8.
__device__ __forceinline__ float4 ld_sys4(const float* p) {
    u64 a = __hip_atomic_load((const u64*)p,       __ATOMIC_RELAXED, __HIP_MEMORY_SCOPE_SYSTEM);
    u64 b = __hip_atomic_load((const u64*)(p + 2), __ATOMIC_RELAXED, __HIP_MEMORY_SCOPE_SYSTEM);
    float4 r;
    r.x = __uint_as_float((uint)a); r.y = __uint_as_float((uint)(a >> 32));
    r.z = __uint_as_float((uint)b); r.w = __uint_as_float((uint)(b >> 32));
    return r;
}
__device__ __forceinline__ void st_sys4(float* p, float4 v) {
    u64 a = ((u64)__float_as_uint(v.y) << 32) | __float_as_uint(v.x);
    u64 b = ((u64)__float_as_uint(v.w) << 32) | __float_as_uint(v.z);
    __hip_atomic_store((u64*)p,       a, __ATOMIC_RELAXED, __HIP_MEMORY_SCOPE_SYSTEM);
    __hip_atomic_store((u64*)(p + 2), b, __ATOMIC_RELAXED, __HIP_MEMORY_SCOPE_SYSTEM);
}

// Pack W1/W2 (both sets) into MFMA B-fragment order in ws (unchanged r4-r8).
__global__ void pack_weights(const float* __restrict__ W1q, const float* __restrict__ W2q,
                             const float* __restrict__ W1p, const float* __restrict__ W2p,
                             char* __restrict__ ws)
{
    const int s = blockIdx.x;
    const float* W1 = s ? W1p : W1q;
    const float* W2 = s ? W2p : W2q;
    ushort* f1 = (ushort*)(ws + (s ? OFF_F1P : OFF_F1Q));
    ushort* f2 = (ushort*)(ws + (s ? OFF_F2P : OFF_F2Q));
    for (int idx = threadIdx.x; idx < 24 * 512; idx += 256) {
        int f = idx >> 9, rem = idx & 511, lane = rem >> 3, j = rem & 7;
        int ks = f >> 3, nt = f & 7;
        int k = ks * 32 + (lane >> 4) * 8 + j, n = nt * 16 + (lane & 15);
        f1[idx] = f2bf(k < DIN ? W1[k * HID + n] : 0.0f);
    }
    for (int idx = threadIdx.x; idx < 8 * 512; idx += 256) {
        int f = idx >> 9, rem = idx & 511, lane = rem >> 3, j = rem & 7;
        int ks = f >> 1, nt = f & 1;
        int k = ks * 32 + (lane >> 4) * 8 + j, n = nt * 16 + (lane & 15);
        f2[idx] = f2bf(W2[k * DD + n]);
    }
}

// Copy initial q/p from x into published buffer 0 (ws).
__global__ void init_state(const float* __restrict__ x, char* __restrict__ ws)
{
    const int blk = blockIdx.x, tid = threadIdx.x;
    const int b = blk >> 6, r = blk & 63;
    const int pt = tid >> 2, sg = (tid & 3) * 8;
    const float* src = x + (size_t)(b * NPTS + r * GRID_W + pt) * DIN;
    float* dst = (float*)(ws + OFF_BUF0) + ((size_t)(b * 64 + r) * 64 + pt) * 64;
    *(float4*)(dst + sg)          = *(const float4*)(src + sg);
    *(float4*)(dst + sg + 4)      = *(const float4*)(src + sg + 4);
    *(float4*)(dst + 32 + sg)     = *(const float4*)(src + DD + sg);
    *(float4*)(dst + 32 + sg + 4) = *(const float4*)(src + DD + sg + 4);
}

struct Acc2 { f32x4 a0, a1; };

// One F-eval for a 64-pt row tile: GEMM1 -> tanh -> sH -> GEMM2. Wave-local sH.
__device__ __forceinline__ Acc2 eval_F(short8 af0, short8 af1, short8 af2,
    const short8* __restrict__ F1, const short8* __restrict__ F2,
    const float* __restrict__ B1, ushort* __restrict__ sH,
    int wv, int lane, int l16, int quad, int q8)
{
    f32x4 acc1[8];
    #pragma unroll
    for (int nt = 0; nt < 8; ++nt) acc1[nt] = (f32x4){0.f, 0.f, 0.f, 0.f};
    #pragma unroll
    for (int nt = 0; nt < 8; ++nt)
        acc1[nt] = __builtin_amdgcn_mfma_f32_16x16x32_bf16(af0, F1[nt * 64 + lane], acc1[nt], 0, 0, 0);
    #pragma unroll
    for (int nt = 0; nt < 8; ++nt)
        acc1[nt] = __builtin_amdgcn_mfma_f32_16x16x32_bf16(af1, F1[(8 + nt) * 64 + lane], acc1[nt], 0, 0, 0);
    #pragma unroll
    for (int nt = 0; nt < 8; ++nt)
        acc1[nt] = __builtin_amdgcn_mfma_f32_16x16x32_bf16(af2, F1[(16 + nt) * 64 + lane], acc1[nt], 0, 0, 0);
    #pragma unroll
    for (int nt = 0; nt < 8; ++nt) {
        const int col = nt * 16 + l16;
        const float bias = B1[col];
        #pragma unroll
        for (int rg = 0; rg < 4; ++rg) {
            const int rowm = wv * 16 + quad * 4 + rg;
            float s = acc1[nt][rg] + bias;
            float e = __expf(2.0f * s);
            float hh = 1.0f - __fdividef(2.0f, e + 1.0f);
            sH[rowm * SH_STRIDE + col] = f2bf(hh);
        }
    }
    Acc2 o;
    o.a0 = (f32x4){0.f, 0.f, 0.f, 0.f};
    o.a1 = (f32x4){0.f, 0.f, 0.f, 0.f};
    #pragma unroll
    for (int ks = 0; ks < 4; ++ks) {
        short8 af = *(const short8*)&sH[(wv * 16 + l16) * SH_STRIDE + ks * 32 + q8];
        o.a0 = __builtin_amdgcn_mfma_f32_16x16x32_bf16(af, F2[(ks * 2 + 0) * 64 + lane], o.a0, 0, 0, 0);
        o.a1 = __builtin_amdgcn_mfma_f32_16x16x32_bf16(af, F2[(ks * 2 + 1) * 64 + lane], o.a1, 0, 0, 0);
    }
    return o;
}

// Halo-1 merged full-step solver: ONE ring sync per leapfrog step.
__global__ __launch_bounds__(256, 2) void sympl_halo(
    float* __restrict__ out, const float* __restrict__ tfinal,
    char* __restrict__ ws,
    const float* __restrict__ b1q, const float* __restrict__ b2q,
    const float* __restrict__ b1p, const float* __restrict__ b2p)
{
    __shared__ __align__(16) float  sQ[64 * SQ_STRIDE];       // own-row q (current)
    __shared__ __align__(16) float  sP[64 * SQ_STRIDE];       // own-row p (current)
    __shared__ __align__(16) float  sPH[2][64 * SQ_STRIDE];   // p_k rows r-1, r+1
    __shared__ __align__(16) ushort sH[64 * SH_STRIDE];
    __shared__ __align__(16) float  qD[2][64 * DD];           // dtq*F deltas, halo rows

    uint* flags = (uint*)ws;
    const int blk = blockIdx.x, tid = threadIdx.x;
    const int b = blk >> 6, r = blk & 63;
    const int wv = tid >> 6, lane = tid & 63;
    const int l16 = lane & 15, quad = lane >> 4, q8 = quad * 8;
    const int c = wv * 16 + l16;
    const int rm1 = (r + 63) & 63, rp1 = (r + 1) & 63;
    const int rm2 = (r + 62) & 63, rp2 = (r + 2) & 63;
    const int cm = (c + 63) & 63, cp = (c + 1) & 63;
    const int pt = tid >> 2, sg = (tid & 3) * 8;

    float* buf0 = (float*)(ws + OFF_BUF0);
    float* buf1 = (float*)(ws + OFF_BUF1);

    // own-row state -> LDS (from pristine d_out copy of x)
    {
        const float* src = out + (size_t)(b * NPTS + r * GRID_W + pt) * DIN;
        *(float4*)&sQ[pt * SQ_STRIDE + sg]     = *(const float4*)(src + sg);
        *(float4*)&sQ[pt * SQ_STRIDE + sg + 4] = *(const float4*)(src + sg + 4);
        *(float4*)&sP[pt * SQ_STRIDE + sg]     = *(const float4*)(src + DD + sg);
        *(float4*)&sP[pt * SQ_STRIDE + sg + 4] = *(const float4*)(src + DD + sg + 4);
    }
    // xi fragments for rows r-1, r, r+1 hoisted (immutable)
    short8 af2m, af2o, af2p;
    if (quad < 2) {
        const float* xm = out + (size_t)(b * NPTS + rm1 * GRID_W + c) * DIN + 2 * DD + q8;
        const float* xo = out + (size_t)(b * NPTS + r   * GRID_W + c) * DIN + 2 * DD + q8;
        const float* xp = out + (size_t)(b * NPTS + rp1 * GRID_W + c) * DIN + 2 * DD + q8;
        af2m = pack8(*(const float4*)xm, *(const float4*)(xm + 4));
        af2o = pack8(*(const float4*)xo, *(const float4*)(xo + 4));
        af2p = pack8(*(const float4*)xp, *(const float4*)(xp + 4));
    } else {
        af2m = af2o = af2p = (short8)(short)0;
    }

    int prow = rm2;
    if (tid == 1) prow = rm1; else if (tid == 2) prow = rp1; else if (tid == 3) prow = rp2;
    uint* pollp = flags + (b * 64 + prow) * 16;
    uint* flO   = flags + blk * 16;

    const short8* F1q = (const short8*)(ws + OFF_F1Q);
    const short8* F2q = (const short8*)(ws + OFF_F2Q);
    const short8* F1p = (const short8*)(ws + OFF_F1P);
    const short8* F2p = (const short8*)(ws + OFF_F2P);

    const float tf = tfinal[b];
    float tq = 0.f, tp = 0.f;

    #pragma unroll 1
    for (int k = 0; k < NFULL; ++k) {
        if (tq >= tf) break;                      // batch-uniform: ring-safe
        const float rhodt = (k == 0) ? 0.125f : 0.25f;
        const float dtq = fminf(tf - tq, rhodt);  // > 0 inside loop (tq<tp+eps)
        const float dtp = fminf(fmaxf(tf - tp, 0.f), 0.25f);

        if (k > 0 && tid < 4) {                   // neighbors r±1, r±2 done k-1
            while (__hip_atomic_load(pollp, __ATOMIC_RELAXED, __HIP_MEMORY_SCOPE_SYSTEM) < (uint)k)
                __builtin_amdgcn_s_sleep(1);
        }
        __syncthreads();

        const float* rbB = (k & 1) ? buf1 : buf0;
        float*       wbB = (k & 1) ? buf0 : buf1;

        // straight-c register loads: p(r±2), q(r±1)
        const float* g_rm2 = rbB + ((size_t)(b * 64 + rm2) * 64 + c) * 64;
        const float* g_rp2 = rbB + ((size_t)(b * 64 + rp2) * 64 + c) * 64;
        const float* g_rm1 = rbB + ((size_t)(b * 64 + rm1) * 64 + c) * 64;
        const float* g_rp1 = rbB + ((size_t)(b * 64 + rp1) * 64 + c) * 64;
        float4 p2u0 = ld_sys4(g_rm2 + 32 + q8), p2u1 = ld_sys4(g_rm2 + 36 + q8);
        float4 p2d0 = ld_sys4(g_rp2 + 32 + q8), p2d1 = ld_sys4(g_rp2 + 36 + q8);
        float4 qu0  = ld_sys4(g_rm1 + q8),      qu1  = ld_sys4(g_rm1 + q8 + 4);
        float4 qd0  = ld_sys4(g_rp1 + q8),      qd1  = ld_sys4(g_rp1 + q8 + 4);
        // stage p_k rows r-1, r+1 into LDS (need c±1 access)
        {
            const float* sm = rbB + ((size_t)(b * 64 + rm1) * 64 + pt) * 64 + 32 + sg;
            const float* sp = rbB + ((size_t)(b * 64 + rp1) * 64 + pt) * 64 + 32 + sg;
            float4 a = ld_sys4(sm), a2 = ld_sys4(sm + 4);
            float4 d = ld_sys4(sp), d2 = ld_sys4(sp + 4);
            *(float4*)&sPH[0][pt * SQ_STRIDE + sg]     = a;
            *(float4*)&sPH[0][pt * SQ_STRIDE + sg + 4] = a2;
            *(float4*)&sPH[1][pt * SQ_STRIDE + sg]     = d;
            *(float4*)&sPH[1][pt * SQ_STRIDE + sg + 4] = d2;
        }
        __syncthreads();

        // ---------------- q phase: evals for rows r-1, r, r+1 ----------------
        {   // row r-1 (halo): up=p(r-2) regs, down=sP, l/r=sPH0
            float4 s0 = *(const float4*)&sPH[0][c * SQ_STRIDE + q8];
            float4 s1 = *(const float4*)&sPH[0][c * SQ_STRIDE + q8 + 4];
            float4 dn0 = *(const float4*)&sP[c * SQ_STRIDE + q8];
            float4 dn1 = *(const float4*)&sP[c * SQ_STRIDE + q8 + 4];
            float4 lf0 = *(const float4*)&sPH[0][cm * SQ_STRIDE + q8];
            float4 lf1 = *(const float4*)&sPH[0][cm * SQ_STRIDE + q8 + 4];
            float4 rt0 = *(const float4*)&sPH[0][cp * SQ_STRIDE + q8];
            float4 rt1 = *(const float4*)&sPH[0][cp * SQ_STRIDE + q8 + 4];
            short8 af0 = pack8(s0, s1);
            short8 af1 = pack8(avg4(p2u0, dn0, lf0, rt0), avg4(p2u1, dn1, lf1, rt1));
            Acc2 A = eval_F(af0, af1, af2m, F1q, F2q, b1q, sH, wv, lane, l16, quad, q8);
            #pragma unroll
            for (int nt = 0; nt < 2; ++nt) {
                const int col = nt * 16 + l16;
                const float b2v = b2q[col];
                const f32x4 av = nt ? A.a1 : A.a0;
                #pragma unroll
                for (int rg = 0; rg < 4; ++rg)
                    qD[0][(wv * 16 + quad * 4 + rg) * DD + col] = dtq * (av[rg] + b2v);
            }
        }
        {   // row r (own): up=sPH0, down=sPH1, l/r=sP -> RMW sQ
            float4 s0 = *(const float4*)&sP[c * SQ_STRIDE + q8];
            float4 s1 = *(const float4*)&sP[c * SQ_STRIDE + q8 + 4];
            float4 up0 = *(const float4*)&sPH[0][c * SQ_STRIDE + q8];
            float4 up1 = *(const float4*)&sPH[0][c * SQ_STRIDE + q8 + 4];
            float4 dn0 = *(const float4*)&sPH[1][c * SQ_STRIDE + q8];
            float4 dn1 = *(const float4*)&sPH[1][c * SQ_STRIDE + q8 + 4];
            float4 lf0 = *(const float4*)&sP[cm * SQ_STRIDE + q8];
            float4 lf1 = *(const float4*)&sP[cm * SQ_STRIDE + q8 + 4];
            float4 rt0 = *(const float4*)&sP[cp * SQ_STRIDE + q8];
            float4 rt1 = *(const float4*)&sP[cp * SQ_STRIDE + q8 + 4];
            short8 af0 = pack8(s0, s1);
            short8 af1 = pack8(avg4(up0, dn0, lf0, rt0), avg4(up1, dn1, lf1, rt1));
            Acc2 A = eval_F(af0, af1, af2o, F1q, F2q, b1q, sH, wv, lane, l16, quad, q8);
            #pragma unroll
            for (int nt = 0; nt < 2; ++nt) {
                const int col = nt * 16 + l16;
                const float b2v = b2q[col];
                const f32x4 av = nt ? A.a1 : A.a0;
                #pragma unroll
                for (int rg = 0; rg < 4; ++rg) {
                    const int m = wv * 16 + quad * 4 + rg;    // wave-private rows
                    sQ[m * SQ_STRIDE + col] += dtq * (av[rg] + b2v);
                }
            }
        }
        {   // row r+1 (halo): up=sP, down=p(r+2) regs, l/r=sPH1
            float4 s0 = *(const float4*)&sPH[1][c * SQ_STRIDE + q8];
            float4 s1 = *(const float4*)&sPH[1][c * SQ_STRIDE + q8 + 4];
            float4 up0 = *(const float4*)&sP[c * SQ_STRIDE + q8];
            float4 up1 = *(const float4*)&sP[c * SQ_STRIDE + q8 + 4];
            float4 lf0 = *(const float4*)&sPH[1][cm * SQ_STRIDE + q8];
            float4 lf1 = *(const float4*)&sPH[1][cm * SQ_STRIDE + q8 + 4];
            float4 rt0 = *(const float4*)&sPH[1][cp * SQ_STRIDE + q8];
            float4 rt1 = *(const float4*)&sPH[1][cp * SQ_STRIDE + q8 + 4];
            short8 af0 = pack8(s0, s1);
            short8 af1 = pack8(avg4(up0, p2d0, lf0, rt0), avg4(up1, p2d1, lf1, rt1));
            Acc2 A = eval_F(af0, af1, af2p, F1q, F2q, b1q, sH, wv, lane, l16, quad, q8);
            #pragma unroll
            for (int nt = 0; nt < 2; ++nt) {
                const int col = nt * 16 + l16;
                const float b2v = b2q[col];
                const f32x4 av = nt ? A.a1 : A.a0;
                #pragma unroll
                for (int rg = 0; rg < 4; ++rg)
                    qD[1][(wv * 16 + quad * 4 + rg) * DD + col] = dtq * (av[rg] + b2v);
            }
        }
        __syncthreads();   // sQ updates + qD visible block-wide

        // ---------------- p phase: row r with q_{k+1} inputs ----------------
        if (dtp > 0.0f) {
            float4 s0 = *(const float4*)&sQ[c * SQ_STRIDE + q8];
            float4 s1 = *(const float4*)&sQ[c * SQ_STRIDE + q8 + 4];
            float4 up0 = addf4(qu0, *(const float4*)&qD[0][c * DD + q8]);
            float4 up1 = addf4(qu1, *(const float4*)&qD[0][c * DD + q8 + 4]);
            float4 dn0 = addf4(qd0, *(const float4*)&qD[1][c * DD + q8]);
            float4 dn1 = addf4(qd1, *(const float4*)&qD[1][c * DD + q8 + 4]);
            float4 lf0 = *(const float4*)&sQ[cm * SQ_STRIDE + q8];
            float4 lf1 = *(const float4*)&sQ[cm * SQ_STRIDE + q8 + 4];
            float4 rt0 = *(const float4*)&sQ[cp * SQ_STRIDE + q8];
            float4 rt1 = *(const float4*)&sQ[cp * SQ_STRIDE + q8 + 4];
            short8 af0 = pack8(s0, s1);
            short8 af1 = pack8(avg4(up0, dn0, lf0, rt0), avg4(up1, dn1, lf1, rt1));
            Acc2 A = eval_F(af0, af1, af2o, F1p, F2p, b1p, sH, wv, lane, l16, quad, q8);
            #pragma unroll
            for (int nt = 0; nt < 2; ++nt) {
                const int col = nt * 16 + l16;
                const float b2v = b2p[col];
                const f32x4 av = nt ? A.a1 : A.a0;
                #pragma unroll
                for (int rg = 0; rg < 4; ++rg) {
                    const int m = wv * 16 + quad * 4 + rg;
                    sP[m * SQ_STRIDE + col] += dtp * (av[rg] + b2v);
                }
            }
        }
        __syncthreads();   // sP stable for cross-wave publish reads

        // ---------------- publish q_{k+1}, p_{k+1} into the other buffer ----
        {
            float* wrow = wbB + ((size_t)(b * 64 + r) * 64 + pt) * 64;
            st_sys4(wrow + sg,          *(const float4*)&sQ[pt * SQ_STRIDE + sg]);
            st_sys4(wrow + sg + 4,      *(const float4*)&sQ[pt * SQ_STRIDE + sg + 4]);
            st_sys4(wrow + 32 + sg,     *(const float4*)&sP[pt * SQ_STRIDE + sg]);
            st_sys4(wrow + 32 + sg + 4, *(const float4*)&sP[pt * SQ_STRIDE + sg + 4]);
        }
        __syncthreads();   // drain all waves' sys stores (vmcnt 0 per wave)
        if (tid == 0)
            __hip_atomic_store(flO, (uint)(k + 1), __ATOMIC_RELAXED, __HIP_MEMORY_SCOPE_SYSTEM);

        tq += rhodt; tp += 0.25f;
    }

    // final state -> d_out (xi already there from the memcpy)
    {
        float* dst = out + (size_t)(b * NPTS + r * GRID_W + pt) * DIN;
        *(float4*)(dst + sg)          = *(const float4*)&sQ[pt * SQ_STRIDE + sg];
        *(float4*)(dst + sg + 4)      = *(const float4*)&sQ[pt * SQ_STRIDE + sg + 4];
        *(float4*)(dst + DD + sg)     = *(const float4*)&sP[pt * SQ_STRIDE + sg];
        *(float4*)(dst + DD + sg + 4) = *(const float4*)&sP[pt * SQ_STRIDE + sg + 4];
    }
}

// ---------------- fallback path (round-8-proven, global state) ----------------
__global__ __launch_bounds__(256, 2) void sympl_step(
    float* __restrict__ state, const float* __restrict__ tfinal,
    const char* __restrict__ ws,
    const float* __restrict__ B1, const float* __restrict__ B2,
    int phase, float tcur, float dtmax)
{
    __shared__ __align__(16) ushort sH[64 * SH_STRIDE];
    __shared__ __align__(16) float  sO[4 * 512];
    const int blk = blockIdx.x, tid = threadIdx.x;
    const int wv = tid >> 6, lane = tid & 63;
    const int l16 = lane & 15, quad = lane >> 4, q8 = quad * 8;
    const int b = blk >> 6, r = blk & 63;
    const int c = wv * 16 + l16;

    const float tf = tfinal[b];
    const float dt = fminf(fmaxf(tf - tcur, 0.0f), dtmax);
    if (dt <= 0.0f) return;

    const int srcoff = phase ? 0 : DD;
    const int dstoff = phase ? DD : 0;
    float* bb = state + (size_t)b * NPTS * DIN;
    const float* selfp = bb + (r * GRID_W + c) * DIN;
    const int rm = (r + 63) & 63, rp = (r + 1) & 63;
    const int cm = (c + 63) & 63, cp = (c + 1) & 63;
    short8 af0, af1, af2;
    {
        const float* ps = selfp + srcoff + q8;
        af0 = pack8(*(const float4*)ps, *(const float4*)(ps + 4));
    }
    {
        const float* p0 = bb + (rm * GRID_W + c) * DIN + srcoff + q8;
        const float* p1 = bb + (rp * GRID_W + c) * DIN + srcoff + q8;
        const float* p2 = bb + (r * GRID_W + cm) * DIN + srcoff + q8;
        const float* p3 = bb + (r * GRID_W + cp) * DIN + srcoff + q8;
        float4 a0 = *(const float4*)p0, a1 = *(const float4*)(p0 + 4);
        float4 b0 = *(const float4*)p1, b1v = *(const float4*)(p1 + 4);
        float4 c0 = *(const float4*)p2, c1 = *(const float4*)(p2 + 4);
        float4 d0 = *(const float4*)p3, d1 = *(const float4*)(p3 + 4);
        af1 = pack8(avg4(a0, b0, c0, d0), avg4(a1, b1v, c1, d1));
    }
    if (quad < 2) {
        const float* px = selfp + 2 * DD + q8;
        af2 = pack8(*(const float4*)px, *(const float4*)(px + 4));
    } else {
        af2 = (short8)(short)0;
    }
    const short8* F1 = (const short8*)(ws + (phase ? OFF_F1P : OFF_F1Q));
    const short8* F2 = (const short8*)(ws + (phase ? OFF_F2P : OFF_F2Q));
    Acc2 A;
    {
        f32x4 acc1[8];
        #pragma unroll
        for (int nt = 0; nt < 8; ++nt) acc1[nt] = (f32x4){0.f, 0.f, 0.f, 0.f};
        #pragma unroll
        for (int nt = 0; nt < 8; ++nt)
            acc1[nt] = __builtin_amdgcn_mfma_f32_16x16x32_bf16(af0, F1[nt * 64 + lane], acc1[nt], 0, 0, 0);
        #pragma unroll
        for (int nt = 0; nt < 8; ++nt)
            acc1[nt] = __builtin_amdgcn_mfma_f32_16x16x32_bf16(af1, F1[(8 + nt) * 64 + lane], acc1[nt], 0, 0, 0);
        #pragma unroll
        for (int nt = 0; nt < 8; ++nt)
            acc1[nt] = __builtin_amdgcn_mfma_f32_16x16x32_bf16(af2, F1[(16 + nt) * 64 + lane], acc1[nt], 0, 0, 0);
        #pragma unroll
        for (int nt = 0; nt < 8; ++nt) {
            const int col = nt * 16 + l16;
            const float bias = B1[col];
            #pragma unroll
            for (int rg = 0; rg < 4; ++rg) {
                const int rowm = wv * 16 + quad * 4 + rg;
                float s = acc1[nt][rg] + bias;
                float e = __expf(2.0f * s);
                float hh = 1.0f - __fdividef(2.0f, e + 1.0f);
                sH[rowm * SH_STRIDE + col] = f2bf(hh);
            }
        }
        A.a0 = (f32x4){0.f, 0.f, 0.f, 0.f};
        A.a1 = (f32x4){0.f, 0.f, 0.f, 0.f};
        #pragma unroll
        for (int ks = 0; ks < 4; ++ks) {
            short8 af = *(const short8*)&sH[(wv * 16 + l16) * SH_STRIDE + ks * 32 + q8];
            A.a0 = __builtin_amdgcn_mfma_f32_16x16x32_bf16(af, F2[(ks * 2 + 0) * 64 + lane], A.a0, 0, 0, 0);
            A.a1 = __builtin_amdgcn_mfma_f32_16x16x32_bf16(af, F2[(ks * 2 + 1) * 64 + lane], A.a1, 0, 0, 0);
        }
    }
    float* sOw = sO + wv * 512;
    #pragma unroll
    for (int nt = 0; nt < 2; ++nt) {
        const int col = nt * 16 + l16;
        const float b2v = B2[col];
        const f32x4 av = nt ? A.a1 : A.a0;
        #pragma unroll
        for (int rg = 0; rg < 4; ++rg)
            sOw[(quad * 4 + rg) * DD + col] = av[rg] + b2v;
    }
    #pragma unroll
    for (int it = 0; it < 2; ++it) {
        const int slot = lane + it * 64;
        const int lr = slot >> 3, seg = (slot & 7) * 4;
        float* pd = bb + (r * GRID_W + wv * 16 + lr) * DIN + dstoff + seg;
        const float* po = &sOw[lr * DD + seg];
        float4 o = *(const float4*)pd;
        o.x += dt * po[0]; o.y += dt * po[1];
        o.z += dt * po[2]; o.w += dt * po[3];
        *(float4*)pd = o;
    }
}

extern "C" void kernel_launch(void* const* d_in, const int* in_sizes, int n_in,
                              void* d_out, int out_size, void* d_ws, size_t ws_size,
                              hipStream_t stream)
{
    const float* x   = (const float*)d_in[0];
    const float* tf  = (const float*)d_in[1];
    const float* W1q = (const float*)d_in[2];
    const float* b1q = (const float*)d_in[3];
    const float* W2q = (const float*)d_in[4];
    const float* b2q = (const float*)d_in[5];
    const float* W1p = (const float*)d_in[6];
    const float* b1p = (const float*)d_in[7];
    const float* W2p = (const float*)d_in[8];
    const float* b2p = (const float*)d_in[9];
    float* out = (float*)d_out;
    char* ws = (char*)d_ws;

    // d_out: [b][i][q(32) p(32) xi(16)] — xi + initial state
    hipMemcpyAsync(out, x, (size_t)BATCH * NPTS * DIN * sizeof(float),
                   hipMemcpyDeviceToDevice, stream);
    hipMemsetAsync(ws, 0, NBLK * 64, stream);          // per-block step flags
    pack_weights<<<dim3(2), dim3(256), 0, stream>>>(W1q, W2q, W1p, W2p, ws);
    init_state<<<dim3(NBLK), dim3(256), 0, stream>>>(x, ws);

    void* args[] = { (void*)&out, (void*)&tf, (void*)&ws,
                     (void*)&b1q, (void*)&b2q, (void*)&b1p, (void*)&b2p };
    hipError_t e = hipLaunchCooperativeKernel((const void*)sympl_halo,
                                              dim3(NBLK), dim3(256), args, 0, stream);
    if (e != hipSuccess) {
        // Fallback: 34 regular launches (kernel-boundary coherence).
        float tq = 0.0f, tp = 0.0f;
        for (int h = 0; h < NSTEP; ++h) {
            const int phase = h & 1;
            const float dtmax = phase ? 0.25f : ((h == 0) ? 0.125f : 0.25f);
            const float tcur  = phase ? tp : tq;
            sympl_step<<<dim3(NBLK), dim3(256), 0, stream>>>(
                out, tf, ws, phase ? b1p : b1q, phase ? b2p : b2q,
                phase, tcur, dtmax);
            if (phase) tp += dtmax; else tq += dtmax;
        }
    }
}

// Round 10
// 283.283 us; speedup vs baseline: 1.7096x; 1.7096x over previous
//
#include <hip/hip_runtime.h>
#include <hip/hip_bf16.h>

#define GRID_W 64
#define NPTS   4096
#define BATCH  8
#define DD     32
#define DIN    80
#define HID    128
#define SH_STRIDE 136              // ushort stride (17*16B) -> conflict-free b128
#define SQ_STRIDE 36               // f32 stride for LDS state rows
#define NBLK   512                 // one grid-row per block
#define NSTEP  34                  // max half-steps for tf <= 4.0
// ws layout: flags (512*64B) | fragment weights | bf16 exchange state
#define OFF_F1Q 32768
#define OFF_F2Q (OFF_F1Q + 24*64*16)
#define OFF_F1P (OFF_F2Q + 8*64*16)
#define OFF_F2P (OFF_F1P + 24*64*16)
#define OFF_EBUF (1 << 17)
// ebuf: [b][row][pt][q(32)|p(32)] bf16 = 8*64*64*64*2 = 4 MB

typedef __attribute__((ext_vector_type(8))) short short8;
typedef __attribute__((ext_vector_type(4))) float f32x4;
typedef unsigned long long u64;

__device__ __forceinline__ ushort f2bf(float v) {
    __hip_bfloat16 h = __float2bfloat16(v);
    return __builtin_bit_cast(ushort, h);
}
__device__ __forceinline__ uint packbf(float a, float b) {
    return (uint)f2bf(a) | ((uint)f2bf(b) << 16);
}
__device__ __forceinline__ short8 pack8(float4 a, float4 b) {
    union { uint u[4]; short8 s; } t;
    t.u[0] = packbf(a.x, a.y); t.u[1] = packbf(a.z, a.w);
    t.u[2] = packbf(b.x, b.y); t.u[3] = packbf(b.z, b.w);
    return t.s;
}
__device__ __forceinline__ float bf2f(ushort u) {
    union { uint i; float f; } t; t.i = ((uint)u) << 16; return t.f;
}

// System-scope (coherence-point) accessors. Proven rounds 5-9.
__device__ __forceinline__ short8 ld_sysh8(const ushort* p) {   // 16B = 8 bf16
    union { u64 v[2]; short8 s; } t;
    t.v[0] = __hip_atomic_load((const u64*)p,       __ATOMIC_RELAXED, __HIP_MEMORY_SCOPE_SYSTEM);
    t.v[1] = __hip_atomic_load((const u64*)(p + 4), __ATOMIC_RELAXED, __HIP_MEMORY_SCOPE_SYSTEM);
    return t.s;
}
__device__ __forceinline__ void st_sysb4(ushort* p, float4 v) { // 8B = 4 bf16
    u64 pk = (u64)packbf(v.x, v.y) | ((u64)packbf(v.z, v.w) << 32);
    __hip_atomic_store((u64*)p, pk, __ATOMIC_RELAXED, __HIP_MEMORY_SCOPE_SYSTEM);
}

// Pack W1/W2 (both sets) into MFMA B-fragment order in ws (unchanged r4-r9).
__global__ void pack_weights(const float* __restrict__ W1q, const float* __restrict__ W2q,
                             const float* __restrict__ W1p, const float* __restrict__ W2p,
                             char* __restrict__ ws)
{
    const int s = blockIdx.x;
    const float* W1 = s ? W1p : W1q;
    const float* W2 = s ? W2p : W2q;
    ushort* f1 = (ushort*)(ws + (s ? OFF_F1P : OFF_F1Q));
    ushort* f2 = (ushort*)(ws + (s ? OFF_F2P : OFF_F2Q));
    for (int idx = threadIdx.x; idx < 24 * 512; idx += 256) {
        int f = idx >> 9, rem = idx & 511, lane = rem >> 3, j = rem & 7;
        int ks = f >> 3, nt = f & 7;
        int k = ks * 32 + (lane >> 4) * 8 + j, n = nt * 16 + (lane & 15);
        f1[idx] = f2bf(k < DIN ? W1[k * HID + n] : 0.0f);
    }
    for (int idx = threadIdx.x; idx < 8 * 512; idx += 256) {
        int f = idx >> 9, rem = idx & 511, lane = rem >> 3, j = rem & 7;
        int ks = f >> 1, nt = f & 1;
        int k = ks * 32 + (lane >> 4) * 8 + j, n = nt * 16 + (lane & 15);
        f2[idx] = f2bf(W2[k * DD + n]);
    }
}

// Initial q/p -> bf16 exchange buffer (plain stores; kernel-end flush
// publishes them — empirically validated in round 9's init_state).
__global__ void init_ebuf(const float* __restrict__ x, char* __restrict__ ws)
{
    const int blk = blockIdx.x, tid = threadIdx.x;
    const int b = blk >> 6, r = blk & 63;
    const int pt = tid >> 2, sg = (tid & 3) * 8;
    const float* src = x + (size_t)(b * NPTS + r * GRID_W + pt) * DIN;
    ushort* drow = (ushort*)(ws + OFF_EBUF) + ((size_t)(b * 64 + r) * 64 + pt) * 64;
    float4 q0 = *(const float4*)(src + sg),      q1 = *(const float4*)(src + sg + 4);
    float4 p0 = *(const float4*)(src + DD + sg), p1 = *(const float4*)(src + DD + sg + 4);
    *(uint*)&drow[sg]          = packbf(q0.x, q0.y);
    *(uint*)&drow[sg + 2]      = packbf(q0.z, q0.w);
    *(uint*)&drow[sg + 4]      = packbf(q1.x, q1.y);
    *(uint*)&drow[sg + 6]      = packbf(q1.z, q1.w);
    *(uint*)&drow[32 + sg]     = packbf(p0.x, p0.y);
    *(uint*)&drow[32 + sg + 2] = packbf(p0.z, p0.w);
    *(uint*)&drow[32 + sg + 4] = packbf(p1.x, p1.y);
    *(uint*)&drow[32 + sg + 6] = packbf(p1.z, p1.w);
}

struct Acc2 { f32x4 a0, a1; };

// One F-eval for a 64-pt row: GEMM1 -> tanh -> sH -> GEMM2. Wave-local sH.
__device__ __forceinline__ Acc2 eval_F(short8 af0, short8 af1, short8 af2,
    const short8* __restrict__ F1, const short8* __restrict__ w2,
    const float* __restrict__ B1, ushort* __restrict__ sH,
    int wv, int lane, int l16, int quad, int q8)
{
    f32x4 acc1[8];
    #pragma unroll
    for (int nt = 0; nt < 8; ++nt) acc1[nt] = (f32x4){0.f, 0.f, 0.f, 0.f};
    #pragma unroll
    for (int nt = 0; nt < 8; ++nt)
        acc1[nt] = __builtin_amdgcn_mfma_f32_16x16x32_bf16(af0, F1[nt * 64 + lane], acc1[nt], 0, 0, 0);
    #pragma unroll
    for (int nt = 0; nt < 8; ++nt)
        acc1[nt] = __builtin_amdgcn_mfma_f32_16x16x32_bf16(af1, F1[(8 + nt) * 64 + lane], acc1[nt], 0, 0, 0);
    #pragma unroll
    for (int nt = 0; nt < 8; ++nt)
        acc1[nt] = __builtin_amdgcn_mfma_f32_16x16x32_bf16(af2, F1[(16 + nt) * 64 + lane], acc1[nt], 0, 0, 0);
    #pragma unroll
    for (int nt = 0; nt < 8; ++nt) {
        const int col = nt * 16 + l16;
        const float bias = B1[col];
        #pragma unroll
        for (int rg = 0; rg < 4; ++rg) {
            const int rowm = wv * 16 + quad * 4 + rg;
            float s = acc1[nt][rg] + bias;
            float e = __expf(2.0f * s);
            float hh = 1.0f - __fdividef(2.0f, e + 1.0f);
            sH[rowm * SH_STRIDE + col] = f2bf(hh);
        }
    }
    Acc2 o;
    o.a0 = (f32x4){0.f, 0.f, 0.f, 0.f};
    o.a1 = (f32x4){0.f, 0.f, 0.f, 0.f};
    #pragma unroll
    for (int ks = 0; ks < 4; ++ks) {
        short8 af = *(const short8*)&sH[(wv * 16 + l16) * SH_STRIDE + ks * 32 + q8];
        o.a0 = __builtin_amdgcn_mfma_f32_16x16x32_bf16(af, w2[ks * 2 + 0], o.a0, 0, 0, 0);
        o.a1 = __builtin_amdgcn_mfma_f32_16x16x32_bf16(af, w2[ks * 2 + 1], o.a1, 0, 0, 0);
    }
    return o;
}

// LDS-resident fp32 state; bf16 neighbor exchange; lag-1 ring sync per half-step.
__global__ __launch_bounds__(256, 2) void sympl_coop(
    float* __restrict__ out, const float* __restrict__ tfinal,
    char* __restrict__ ws,
    const float* __restrict__ b1q, const float* __restrict__ b2q,
    const float* __restrict__ b1p, const float* __restrict__ b2p)
{
    __shared__ __align__(16) float  sQ[64 * SQ_STRIDE];
    __shared__ __align__(16) float  sP[64 * SQ_STRIDE];
    __shared__ __align__(16) ushort sH[64 * SH_STRIDE];
    __shared__ __align__(16) float  sO[4 * 512];

    uint* flags = (uint*)ws;
    ushort* ebuf = (ushort*)(ws + OFF_EBUF);
    const int blk = blockIdx.x, tid = threadIdx.x;
    const int b = blk >> 6, r = blk & 63;
    const int wv = tid >> 6, lane = tid & 63;
    const int l16 = lane & 15, quad = lane >> 4, q8 = quad * 8;
    const int c = wv * 16 + l16;
    const int rm = (r + 63) & 63, rp = (r + 1) & 63;
    const int cm = (c + 63) & 63, cp = (c + 1) & 63;
    const int pt = tid >> 2, sg = (tid & 3) * 8;

    uint* flL = flags + (b * 64 + rm) * 16;
    uint* flR = flags + (b * 64 + rp) * 16;
    uint* flO = flags + blk * 16;
    uint* myflag = (tid == 0) ? flL : flR;

    // ---- init: own-row q/p -> LDS fp32; xi + W2 fragments -> registers ----
    {
        const float* src = out + (size_t)(b * NPTS + r * GRID_W + pt) * DIN;
        *(float4*)&sQ[pt * SQ_STRIDE + sg]     = *(const float4*)(src + sg);
        *(float4*)&sQ[pt * SQ_STRIDE + sg + 4] = *(const float4*)(src + sg + 4);
        *(float4*)&sP[pt * SQ_STRIDE + sg]     = *(const float4*)(src + DD + sg);
        *(float4*)&sP[pt * SQ_STRIDE + sg + 4] = *(const float4*)(src + DD + sg + 4);
    }
    short8 af2;
    if (quad < 2) {
        const float* px = out + (size_t)(b * NPTS + r * GRID_W + c) * DIN + 2 * DD + q8;
        af2 = pack8(*(const float4*)px, *(const float4*)(px + 4));
    } else {
        af2 = (short8)(short)0;
    }
    short8 w2q[8], w2p[8];
    {
        const short8* F2q = (const short8*)(ws + OFF_F2Q);
        const short8* F2p = (const short8*)(ws + OFF_F2P);
        #pragma unroll
        for (int i = 0; i < 8; ++i) { w2q[i] = F2q[i * 64 + lane]; w2p[i] = F2p[i * 64 + lane]; }
    }
    const float tf = tfinal[b];
    __syncthreads();

    const ushort* e_rm = ebuf + ((size_t)(b * 64 + rm) * 64 + c) * 64;
    const ushort* e_rp = ebuf + ((size_t)(b * 64 + rp) * 64 + c) * 64;

    float tq = 0.0f, tp = 0.0f;
    #pragma unroll 1
    for (int h = 0; h < NSTEP; ++h) {
        const int phase = h & 1;           // 0: q += dt*F(p); 1: p += dt*F(q)
        const float dtmax = phase ? 0.25f : ((h == 0) ? 0.125f : 0.25f);
        const float tcur  = phase ? tp : tq;
        if (!phase && tq >= tf) break;     // batch-uniform: ring stays deadlock-free
        if (h > 0 && tid < 2) {            // neighbors completed half-step h-1
            while (__hip_atomic_load(myflag, __ATOMIC_RELAXED, __HIP_MEMORY_SCOPE_SYSTEM) < (uint)h)
                __builtin_amdgcn_s_sleep(1);
        }
        __syncthreads();

        const float dt = fminf(fmaxf(tf - tcur, 0.0f), dtmax);
        if (dt > 0.0f) {                   // block-uniform
            const int so  = phase ? 0 : 32;    // src half in ebuf (q:0, p:32)
            const int dso = phase ? 32 : 0;    // dst half in ebuf
            const float* srcL = phase ? sQ : sP;
            float*       dstL = phase ? sP : sQ;

            // ---- neighbor rows (bf16, sys-scope; issue first) ----
            short8 upv = ld_sysh8(e_rm + so + q8);
            short8 dnv = ld_sysh8(e_rp + so + q8);

            // ---- self + column neighbors from LDS fp32 ----
            const float* s0p = srcL + c  * SQ_STRIDE + q8;
            const float* smp = srcL + cm * SQ_STRIDE + q8;
            const float* spp = srcL + cp * SQ_STRIDE + q8;
            float4 a0 = *(const float4*)s0p, a1 = *(const float4*)(s0p + 4);
            float4 lf0 = *(const float4*)smp, lf1 = *(const float4*)(smp + 4);
            float4 rt0 = *(const float4*)spp, rt1 = *(const float4*)(spp + 4);
            float4 m0, m1;
            m0.x = 0.25f * (bf2f((ushort)upv[0]) + bf2f((ushort)dnv[0]) + lf0.x + rt0.x);
            m0.y = 0.25f * (bf2f((ushort)upv[1]) + bf2f((ushort)dnv[1]) + lf0.y + rt0.y);
            m0.z = 0.25f * (bf2f((ushort)upv[2]) + bf2f((ushort)dnv[2]) + lf0.z + rt0.z);
            m0.w = 0.25f * (bf2f((ushort)upv[3]) + bf2f((ushort)dnv[3]) + lf0.w + rt0.w);
            m1.x = 0.25f * (bf2f((ushort)upv[4]) + bf2f((ushort)dnv[4]) + lf1.x + rt1.x);
            m1.y = 0.25f * (bf2f((ushort)upv[5]) + bf2f((ushort)dnv[5]) + lf1.y + rt1.y);
            m1.z = 0.25f * (bf2f((ushort)upv[6]) + bf2f((ushort)dnv[6]) + lf1.z + rt1.z);
            m1.w = 0.25f * (bf2f((ushort)upv[7]) + bf2f((ushort)dnv[7]) + lf1.w + rt1.w);
            short8 af0 = pack8(a0, a1);
            short8 af1 = pack8(m0, m1);

            const short8* F1 = (const short8*)(ws + (phase ? OFF_F1P : OFF_F1Q));
            Acc2 A = eval_F(af0, af1, af2, F1, phase ? w2p : w2q,
                            phase ? b1p : b1q, sH, wv, lane, l16, quad, q8);

            // ---- O -> wave-private sO ----
            float* sOw = sO + wv * 512;
            const float* B2 = phase ? b2p : b2q;
            #pragma unroll
            for (int nt = 0; nt < 2; ++nt) {
                const int col = nt * 16 + l16;
                const float b2v = B2[col];
                const f32x4 av = nt ? A.a1 : A.a0;
                #pragma unroll
                for (int rg = 0; rg < 4; ++rg)
                    sOw[(quad * 4 + rg) * DD + col] = av[rg] + b2v;
            }
            // ---- LDS fp32 RMW + bf16 publish (piggybacked, 8B sys-store) ----
            #pragma unroll
            for (int it = 0; it < 2; ++it) {
                const int slot = lane + it * 64;   // 128 float4 slots = 16 rows x 8
                const int lr = slot >> 3, seg = (slot & 7) * 4;
                const int pt_ = wv * 16 + lr;      // wave-private rows: no race
                const float* po = &sOw[lr * DD + seg];
                float* pl = dstL + pt_ * SQ_STRIDE + seg;
                float4 o = *(const float4*)pl;
                o.x += dt * po[0]; o.y += dt * po[1];
                o.z += dt * po[2]; o.w += dt * po[3];
                *(float4*)pl = o;
                st_sysb4(ebuf + ((size_t)(b * 64 + r) * 64 + pt_) * 64 + dso + seg, o);
            }
        }
        __syncthreads();                   // drain all waves' sys stores (vmcnt 0)
        if (tid == 0)
            __hip_atomic_store(flO, (uint)(h + 1), __ATOMIC_RELAXED, __HIP_MEMORY_SCOPE_SYSTEM);
        if (phase) tp += dtmax; else tq += dtmax;
    }

    // ---- final state -> d_out (xi already there from the memcpy) ----
    {
        float* dst = out + (size_t)(b * NPTS + r * GRID_W + pt) * DIN;
        *(float4*)(dst + sg)          = *(const float4*)&sQ[pt * SQ_STRIDE + sg];
        *(float4*)(dst + sg + 4)      = *(const float4*)&sQ[pt * SQ_STRIDE + sg + 4];
        *(float4*)(dst + DD + sg)     = *(const float4*)&sP[pt * SQ_STRIDE + sg];
        *(float4*)(dst + DD + sg + 4) = *(const float4*)&sP[pt * SQ_STRIDE + sg + 4];
    }
}

// ---------------- fallback path (round-8-proven, global fp32 state) ----------------
__global__ __launch_bounds__(256, 2) void sympl_step(
    float* __restrict__ state, const float* __restrict__ tfinal,
    const char* __restrict__ ws,
    const float* __restrict__ B1, const float* __restrict__ B2,
    int phase, float tcur, float dtmax)
{
    __shared__ __align__(16) ushort sH[64 * SH_STRIDE];
    __shared__ __align__(16) float  sO[4 * 512];
    const int blk = blockIdx.x, tid = threadIdx.x;
    const int wv = tid >> 6, lane = tid & 63;
    const int l16 = lane & 15, quad = lane >> 4, q8 = quad * 8;
    const int b = blk >> 6, r = blk & 63;
    const int c = wv * 16 + l16;

    const float tf = tfinal[b];
    const float dt = fminf(fmaxf(tf - tcur, 0.0f), dtmax);
    if (dt <= 0.0f) return;

    const int srcoff = phase ? 0 : DD;
    const int dstoff = phase ? DD : 0;
    float* bb = state + (size_t)b * NPTS * DIN;
    const float* selfp = bb + (r * GRID_W + c) * DIN;
    const int rm = (r + 63) & 63, rp = (r + 1) & 63;
    const int cm = (c + 63) & 63, cp = (c + 1) & 63;
    short8 af0, af1, af2;
    {
        const float* ps = selfp + srcoff + q8;
        af0 = pack8(*(const float4*)ps, *(const float4*)(ps + 4));
    }
    {
        const float* p0 = bb + (rm * GRID_W + c) * DIN + srcoff + q8;
        const float* p1 = bb + (rp * GRID_W + c) * DIN + srcoff + q8;
        const float* p2 = bb + (r * GRID_W + cm) * DIN + srcoff + q8;
        const float* p3 = bb + (r * GRID_W + cp) * DIN + srcoff + q8;
        float4 a0 = *(const float4*)p0, a1 = *(const float4*)(p0 + 4);
        float4 b0 = *(const float4*)p1, b1v = *(const float4*)(p1 + 4);
        float4 c0 = *(const float4*)p2, c1 = *(const float4*)(p2 + 4);
        float4 d0 = *(const float4*)p3, d1 = *(const float4*)(p3 + 4);
        float4 m0, m1;
        m0.x = 0.25f * (a0.x + b0.x + c0.x + d0.x);
        m0.y = 0.25f * (a0.y + b0.y + c0.y + d0.y);
        m0.z = 0.25f * (a0.z + b0.z + c0.z + d0.z);
        m0.w = 0.25f * (a0.w + b0.w + c0.w + d0.w);
        m1.x = 0.25f * (a1.x + b1v.x + c1.x + d1.x);
        m1.y = 0.25f * (a1.y + b1v.y + c1.y + d1.y);
        m1.z = 0.25f * (a1.z + b1v.z + c1.z + d1.z);
        m1.w = 0.25f * (a1.w + b1v.w + c1.w + d1.w);
        af1 = pack8(m0, m1);
    }
    if (quad < 2) {
        const float* px = selfp + 2 * DD + q8;
        af2 = pack8(*(const float4*)px, *(const float4*)(px + 4));
    } else {
        af2 = (short8)(short)0;
    }
    const short8* F1 = (const short8*)(ws + (phase ? OFF_F1P : OFF_F1Q));
    const short8* F2 = (const short8*)(ws + (phase ? OFF_F2P : OFF_F2Q));
    short8 w2[8];
    #pragma unroll
    for (int i = 0; i < 8; ++i) w2[i] = F2[i * 64 + lane];
    Acc2 A = eval_F(af0, af1, af2, F1, w2, B1, sH, wv, lane, l16, quad, q8);
    float* sOw = sO + wv * 512;
    #pragma unroll
    for (int nt = 0; nt < 2; ++nt) {
        const int col = nt * 16 + l16;
        const float b2v = B2[col];
        const f32x4 av = nt ? A.a1 : A.a0;
        #pragma unroll
        for (int rg = 0; rg < 4; ++rg)
            sOw[(quad * 4 + rg) * DD + col] = av[rg] + b2v;
    }
    #pragma unroll
    for (int it = 0; it < 2; ++it) {
        const int slot = lane + it * 64;
        const int lr = slot >> 3, seg = (slot & 7) * 4;
        float* pd = bb + (r * GRID_W + wv * 16 + lr) * DIN + dstoff + seg;
        const float* po = &sOw[lr * DD + seg];
        float4 o = *(const float4*)pd;
        o.x += dt * po[0]; o.y += dt * po[1];
        o.z += dt * po[2]; o.w += dt * po[3];
        *(float4*)pd = o;
    }
}

extern "C" void kernel_launch(void* const* d_in, const int* in_sizes, int n_in,
                              void* d_out, int out_size, void* d_ws, size_t ws_size,
                              hipStream_t stream)
{
    const float* x   = (const float*)d_in[0];
    const float* tf  = (const float*)d_in[1];
    const float* W1q = (const float*)d_in[2];
    const float* b1q = (const float*)d_in[3];
    const float* W2q = (const float*)d_in[4];
    const float* b2q = (const float*)d_in[5];
    const float* W1p = (const float*)d_in[6];
    const float* b1p = (const float*)d_in[7];
    const float* W2p = (const float*)d_in[8];
    const float* b2p = (const float*)d_in[9];
    float* out = (float*)d_out;
    char* ws = (char*)d_ws;

    // d_out: [b][i][q(32) p(32) xi(16)] — xi + initial state
    hipMemcpyAsync(out, x, (size_t)BATCH * NPTS * DIN * sizeof(float),
                   hipMemcpyDeviceToDevice, stream);
    hipMemsetAsync(ws, 0, NBLK * 64, stream);          // per-block step flags
    pack_weights<<<dim3(2), dim3(256), 0, stream>>>(W1q, W2q, W1p, W2p, ws);
    init_ebuf<<<dim3(NBLK), dim3(256), 0, stream>>>(x, ws);

    void* args[] = { (void*)&out, (void*)&tf, (void*)&ws,
                     (void*)&b1q, (void*)&b2q, (void*)&b1p, (void*)&b2p };
    hipError_t e = hipLaunchCooperativeKernel((const void*)sympl_coop,
                                              dim3(NBLK), dim3(256), args, 0, stream);
    if (e != hipSuccess) {
        // Fallback: 34 regular launches (kernel-boundary coherence).
        float tq = 0.0f, tp = 0.0f;
        for (int h = 0; h < NSTEP; ++h) {
            const int phase = h & 1;
            const float dtmax = phase ? 0.25f : ((h == 0) ? 0.125f : 0.25f);
            const float tcur  = phase ? tp : tq;
            sympl_step<<<dim3(NBLK), dim3(256), 0, stream>>>(
                out, tf, ws, phase ? b1p : b1q, phase ? b2p : b2q,
                phase, tcur, dtmax);
            if (phase) tp += dtmax; else tq += dtmax;
        }
    }
}

// Round 11
// 250.964 us; speedup vs baseline: 1.9297x; 1.1288x over previous
//
#include <hip/hip_runtime.h>
#include <hip/hip_bf16.h>

#define GRID_W 64
#define NPTS   4096
#define BATCH  8
#define DD     32
#define DIN    80
#define HID    128
#define SH_STRIDE 136              // ushort stride (17*16B) -> conflict-free b128
#define SQ_STRIDE 36               // f32 stride for LDS state rows
#define NBLK   512                 // one grid-row per block
#define NSTEP  34                  // max half-steps for tf <= 4.0
// ws layout: per-WAVE flags (512 blk * 4 waves * 64B = 128 KB) | fragments | ebuf
#define OFF_F1Q 131072
#define OFF_F2Q (OFF_F1Q + 24*64*16)
#define OFF_F1P (OFF_F2Q + 8*64*16)
#define OFF_F2P (OFF_F1P + 24*64*16)
#define OFF_EBUF 262144
// ebuf: [b][row][pt][q(32)|p(32)] bf16 = 8*64*64*64*2 = 4 MB

typedef __attribute__((ext_vector_type(8))) short short8;
typedef __attribute__((ext_vector_type(4))) float f32x4;
typedef unsigned long long u64;

__device__ __forceinline__ ushort f2bf(float v) {
    __hip_bfloat16 h = __float2bfloat16(v);
    return __builtin_bit_cast(ushort, h);
}
__device__ __forceinline__ uint packbf(float a, float b) {
    return (uint)f2bf(a) | ((uint)f2bf(b) << 16);
}
__device__ __forceinline__ short8 pack8(float4 a, float4 b) {
    union { uint u[4]; short8 s; } t;
    t.u[0] = packbf(a.x, a.y); t.u[1] = packbf(a.z, a.w);
    t.u[2] = packbf(b.x, b.y); t.u[3] = packbf(b.z, b.w);
    return t.s;
}
__device__ __forceinline__ float bf2f(ushort u) {
    union { uint i; float f; } t; t.i = ((uint)u) << 16; return t.f;
}

// System-scope (coherence-point) accessors. Proven rounds 5-10.
__device__ __forceinline__ short8 ld_sysh8(const ushort* p) {   // 16B = 8 bf16
    union { u64 v[2]; short8 s; } t;
    t.v[0] = __hip_atomic_load((const u64*)p,       __ATOMIC_RELAXED, __HIP_MEMORY_SCOPE_SYSTEM);
    t.v[1] = __hip_atomic_load((const u64*)(p + 4), __ATOMIC_RELAXED, __HIP_MEMORY_SCOPE_SYSTEM);
    return t.s;
}
__device__ __forceinline__ void st_sysb4(ushort* p, float4 v) { // 8B = 4 bf16
    u64 pk = (u64)packbf(v.x, v.y) | ((u64)packbf(v.z, v.w) << 32);
    __hip_atomic_store((u64*)p, pk, __ATOMIC_RELAXED, __HIP_MEMORY_SCOPE_SYSTEM);
}

// Pack W1/W2 (both sets) into MFMA B-fragment order in ws (unchanged r4-r10).
__global__ void pack_weights(const float* __restrict__ W1q, const float* __restrict__ W2q,
                             const float* __restrict__ W1p, const float* __restrict__ W2p,
                             char* __restrict__ ws)
{
    const int s = blockIdx.x;
    const float* W1 = s ? W1p : W1q;
    const float* W2 = s ? W2p : W2q;
    ushort* f1 = (ushort*)(ws + (s ? OFF_F1P : OFF_F1Q));
    ushort* f2 = (ushort*)(ws + (s ? OFF_F2P : OFF_F2Q));
    for (int idx = threadIdx.x; idx < 24 * 512; idx += 256) {
        int f = idx >> 9, rem = idx & 511, lane = rem >> 3, j = rem & 7;
        int ks = f >> 3, nt = f & 7;
        int k = ks * 32 + (lane >> 4) * 8 + j, n = nt * 16 + (lane & 15);
        f1[idx] = f2bf(k < DIN ? W1[k * HID + n] : 0.0f);
    }
    for (int idx = threadIdx.x; idx < 8 * 512; idx += 256) {
        int f = idx >> 9, rem = idx & 511, lane = rem >> 3, j = rem & 7;
        int ks = f >> 1, nt = f & 1;
        int k = ks * 32 + (lane >> 4) * 8 + j, n = nt * 16 + (lane & 15);
        f2[idx] = f2bf(W2[k * DD + n]);
    }
}

// Initial q/p -> bf16 exchange buffer.
__global__ void init_ebuf(const float* __restrict__ x, char* __restrict__ ws)
{
    const int blk = blockIdx.x, tid = threadIdx.x;
    const int b = blk >> 6, r = blk & 63;
    const int pt = tid >> 2, sg = (tid & 3) * 8;
    const float* src = x + (size_t)(b * NPTS + r * GRID_W + pt) * DIN;
    ushort* drow = (ushort*)(ws + OFF_EBUF) + ((size_t)(b * 64 + r) * 64 + pt) * 64;
    float4 q0 = *(const float4*)(src + sg),      q1 = *(const float4*)(src + sg + 4);
    float4 p0 = *(const float4*)(src + DD + sg), p1 = *(const float4*)(src + DD + sg + 4);
    *(uint*)&drow[sg]          = packbf(q0.x, q0.y);
    *(uint*)&drow[sg + 2]      = packbf(q0.z, q0.w);
    *(uint*)&drow[sg + 4]      = packbf(q1.x, q1.y);
    *(uint*)&drow[sg + 6]      = packbf(q1.z, q1.w);
    *(uint*)&drow[32 + sg]     = packbf(p0.x, p0.y);
    *(uint*)&drow[32 + sg + 2] = packbf(p0.z, p0.w);
    *(uint*)&drow[32 + sg + 4] = packbf(p1.x, p1.y);
    *(uint*)&drow[32 + sg + 6] = packbf(p1.z, p1.w);
}

struct Acc2 { f32x4 a0, a1; };

// (fallback-only) full F-eval helper
__device__ __forceinline__ Acc2 eval_F(short8 af0, short8 af1, short8 af2,
    const short8* __restrict__ F1, const short8* __restrict__ w2,
    const float* __restrict__ B1, ushort* __restrict__ sH,
    int wv, int lane, int l16, int quad, int q8)
{
    f32x4 acc1[8];
    #pragma unroll
    for (int nt = 0; nt < 8; ++nt) acc1[nt] = (f32x4){0.f, 0.f, 0.f, 0.f};
    #pragma unroll
    for (int nt = 0; nt < 8; ++nt)
        acc1[nt] = __builtin_amdgcn_mfma_f32_16x16x32_bf16(af0, F1[nt * 64 + lane], acc1[nt], 0, 0, 0);
    #pragma unroll
    for (int nt = 0; nt < 8; ++nt)
        acc1[nt] = __builtin_amdgcn_mfma_f32_16x16x32_bf16(af1, F1[(8 + nt) * 64 + lane], acc1[nt], 0, 0, 0);
    #pragma unroll
    for (int nt = 0; nt < 8; ++nt)
        acc1[nt] = __builtin_amdgcn_mfma_f32_16x16x32_bf16(af2, F1[(16 + nt) * 64 + lane], acc1[nt], 0, 0, 0);
    #pragma unroll
    for (int nt = 0; nt < 8; ++nt) {
        const int col = nt * 16 + l16;
        const float bias = B1[col];
        #pragma unroll
        for (int rg = 0; rg < 4; ++rg) {
            const int rowm = wv * 16 + quad * 4 + rg;
            float s = acc1[nt][rg] + bias;
            float e = __expf(2.0f * s);
            float hh = 1.0f - __fdividef(2.0f, e + 1.0f);
            sH[rowm * SH_STRIDE + col] = f2bf(hh);
        }
    }
    Acc2 o;
    o.a0 = (f32x4){0.f, 0.f, 0.f, 0.f};
    o.a1 = (f32x4){0.f, 0.f, 0.f, 0.f};
    #pragma unroll
    for (int ks = 0; ks < 4; ++ks) {
        short8 af = *(const short8*)&sH[(wv * 16 + l16) * SH_STRIDE + ks * 32 + q8];
        o.a0 = __builtin_amdgcn_mfma_f32_16x16x32_bf16(af, w2[ks * 2 + 0], o.a0, 0, 0, 0);
        o.a1 = __builtin_amdgcn_mfma_f32_16x16x32_bf16(af, w2[ks * 2 + 1], o.a1, 0, 0, 0);
    }
    return o;
}

// Wave-autonomous rings: per-wave L3 flags for row neighbors, per-wave LDS
// flags for intra-block column-boundary waves. NO __syncthreads in the loop.
__global__ __launch_bounds__(256, 2) void sympl_coop(
    float* __restrict__ out, const float* __restrict__ tfinal,
    char* __restrict__ ws,
    const float* __restrict__ b1q, const float* __restrict__ b2q,
    const float* __restrict__ b1p, const float* __restrict__ b2p)
{
    __shared__ __align__(16) float  sQ[64 * SQ_STRIDE];
    __shared__ __align__(16) float  sP[64 * SQ_STRIDE];
    __shared__ __align__(16) ushort sH[64 * SH_STRIDE];
    __shared__ __align__(16) float  sO[4 * 512];
    __shared__ uint ldsF[4];

    uint* flags = (uint*)ws;
    ushort* ebuf = (ushort*)(ws + OFF_EBUF);
    const int blk = blockIdx.x, tid = threadIdx.x;
    const int b = blk >> 6, r = blk & 63;
    const int wv = tid >> 6, lane = tid & 63;
    const int l16 = lane & 15, quad = lane >> 4, q8 = quad * 8;
    const int c = wv * 16 + l16;
    const int rm = (r + 63) & 63, rp = (r + 1) & 63;
    const int cm = (c + 63) & 63, cp = (c + 1) & 63;
    const int pt = tid >> 2, sg = (tid & 3) * 8;

    uint* flLw = flags + (((size_t)(b * 64 + rm) * 4) + wv) * 16;
    uint* flRw = flags + (((size_t)(b * 64 + rp) * 4) + wv) * 16;
    uint* flOw = flags + (((size_t)(b * 64 + r ) * 4) + wv) * 16;

    // ---- init: own-row q/p -> LDS fp32; xi + W2 fragments -> registers ----
    {
        const float* src = out + (size_t)(b * NPTS + r * GRID_W + pt) * DIN;
        *(float4*)&sQ[pt * SQ_STRIDE + sg]     = *(const float4*)(src + sg);
        *(float4*)&sQ[pt * SQ_STRIDE + sg + 4] = *(const float4*)(src + sg + 4);
        *(float4*)&sP[pt * SQ_STRIDE + sg]     = *(const float4*)(src + DD + sg);
        *(float4*)&sP[pt * SQ_STRIDE + sg + 4] = *(const float4*)(src + DD + sg + 4);
    }
    if (tid < 4) ldsF[tid] = 0;
    short8 af2;
    if (quad < 2) {
        const float* px = out + (size_t)(b * NPTS + r * GRID_W + c) * DIN + 2 * DD + q8;
        af2 = pack8(*(const float4*)px, *(const float4*)(px + 4));
    } else {
        af2 = (short8)(short)0;
    }
    short8 w2q[8], w2p[8];
    {
        const short8* F2q = (const short8*)(ws + OFF_F2Q);
        const short8* F2p = (const short8*)(ws + OFF_F2P);
        #pragma unroll
        for (int i = 0; i < 8; ++i) { w2q[i] = F2q[i * 64 + lane]; w2p[i] = F2p[i * 64 + lane]; }
    }
    const float tf = tfinal[b];
    __syncthreads();                        // LDS state + ldsF visible

    const ushort* e_rm = ebuf + ((size_t)(b * 64 + rm) * 64 + c) * 64;
    const ushort* e_rp = ebuf + ((size_t)(b * 64 + rp) * 64 + c) * 64;
    const int wl = (wv + 3) & 3, wr = (wv + 1) & 3;

    float tq = 0.0f, tp = 0.0f;
    #pragma unroll 1
    for (int h = 0; h < NSTEP; ++h) {
        const int phase = h & 1;            // 0: q += dt*F(p); 1: p += dt*F(q)
        const float dtmax = phase ? 0.25f : ((h == 0) ? 0.125f : 0.25f);
        const float tcur  = phase ? tp : tq;
        if (!phase && tq >= tf) break;      // batch-uniform: all rings exit together
        if (h > 0) {                        // wave-level lag-1 wait: rows r±1 (L3), waves wv±1 (LDS)
            const uint tgt = (uint)h;
            while (true) {
                uint v = tgt;
                if (lane == 0)      v = __hip_atomic_load(flLw, __ATOMIC_RELAXED, __HIP_MEMORY_SCOPE_SYSTEM);
                else if (lane == 1) v = __hip_atomic_load(flRw, __ATOMIC_RELAXED, __HIP_MEMORY_SCOPE_SYSTEM);
                else if (lane == 2) v = __hip_atomic_load(&ldsF[wl], __ATOMIC_RELAXED, __HIP_MEMORY_SCOPE_WORKGROUP);
                else if (lane == 3) v = __hip_atomic_load(&ldsF[wr], __ATOMIC_RELAXED, __HIP_MEMORY_SCOPE_WORKGROUP);
                if (__all((int)(v >= tgt))) break;
                __builtin_amdgcn_s_sleep(1);
            }
        }

        const float dt = fminf(fmaxf(tf - tcur, 0.0f), dtmax);
        if (dt > 0.0f) {                    // block-uniform
            const int so  = phase ? 0 : 32;     // src half in ebuf (q:0, p:32)
            const int dso = phase ? 32 : 0;     // dst half
            const float* srcL = phase ? sQ : sP;
            float*       dstL = phase ? sP : sQ;

            // neighbor rows (bf16, sys; issue FIRST, consumed LAST)
            short8 upv = ld_sysh8(e_rm + so + q8);
            short8 dnv = ld_sysh8(e_rp + so + q8);

            // self from LDS -> af0; run af0+af2 MFMAs while loads fly
            const float* s0p = srcL + c * SQ_STRIDE + q8;
            float4 a0 = *(const float4*)s0p, a1 = *(const float4*)(s0p + 4);
            short8 af0 = pack8(a0, a1);

            const short8* F1 = (const short8*)(ws + (phase ? OFF_F1P : OFF_F1Q));
            f32x4 acc1[8];
            #pragma unroll
            for (int nt = 0; nt < 8; ++nt) acc1[nt] = (f32x4){0.f, 0.f, 0.f, 0.f};
            #pragma unroll
            for (int nt = 0; nt < 8; ++nt)
                acc1[nt] = __builtin_amdgcn_mfma_f32_16x16x32_bf16(af0, F1[nt * 64 + lane], acc1[nt], 0, 0, 0);
            #pragma unroll
            for (int nt = 0; nt < 8; ++nt)
                acc1[nt] = __builtin_amdgcn_mfma_f32_16x16x32_bf16(af2, F1[(16 + nt) * 64 + lane], acc1[nt], 0, 0, 0);

            // column neighbors (LDS) + row neighbors (loads) -> af1, last
            const float* smp = srcL + cm * SQ_STRIDE + q8;
            const float* spp = srcL + cp * SQ_STRIDE + q8;
            float4 lf0 = *(const float4*)smp, lf1 = *(const float4*)(smp + 4);
            float4 rt0 = *(const float4*)spp, rt1 = *(const float4*)(spp + 4);
            float4 m0, m1;
            m0.x = 0.25f * (bf2f((ushort)upv[0]) + bf2f((ushort)dnv[0]) + lf0.x + rt0.x);
            m0.y = 0.25f * (bf2f((ushort)upv[1]) + bf2f((ushort)dnv[1]) + lf0.y + rt0.y);
            m0.z = 0.25f * (bf2f((ushort)upv[2]) + bf2f((ushort)dnv[2]) + lf0.z + rt0.z);
            m0.w = 0.25f * (bf2f((ushort)upv[3]) + bf2f((ushort)dnv[3]) + lf0.w + rt0.w);
            m1.x = 0.25f * (bf2f((ushort)upv[4]) + bf2f((ushort)dnv[4]) + lf1.x + rt1.x);
            m1.y = 0.25f * (bf2f((ushort)upv[5]) + bf2f((ushort)dnv[5]) + lf1.y + rt1.y);
            m1.z = 0.25f * (bf2f((ushort)upv[6]) + bf2f((ushort)dnv[6]) + lf1.z + rt1.z);
            m1.w = 0.25f * (bf2f((ushort)upv[7]) + bf2f((ushort)dnv[7]) + lf1.w + rt1.w);
            short8 af1 = pack8(m0, m1);
            #pragma unroll
            for (int nt = 0; nt < 8; ++nt)
                acc1[nt] = __builtin_amdgcn_mfma_f32_16x16x32_bf16(af1, F1[(8 + nt) * 64 + lane], acc1[nt], 0, 0, 0);

            // tanh -> sH (wave-local rows)
            const float* B1 = phase ? b1p : b1q;
            #pragma unroll
            for (int nt = 0; nt < 8; ++nt) {
                const int col = nt * 16 + l16;
                const float bias = B1[col];
                #pragma unroll
                for (int rg = 0; rg < 4; ++rg) {
                    const int rowm = wv * 16 + quad * 4 + rg;
                    float s = acc1[nt][rg] + bias;
                    float e = __expf(2.0f * s);
                    float hh = 1.0f - __fdividef(2.0f, e + 1.0f);
                    sH[rowm * SH_STRIDE + col] = f2bf(hh);
                }
            }
            // GEMM2 (register-resident W2)
            const short8* w2 = phase ? w2p : w2q;
            f32x4 o0 = (f32x4){0.f, 0.f, 0.f, 0.f};
            f32x4 o1 = (f32x4){0.f, 0.f, 0.f, 0.f};
            #pragma unroll
            for (int ks = 0; ks < 4; ++ks) {
                short8 af = *(const short8*)&sH[(wv * 16 + l16) * SH_STRIDE + ks * 32 + q8];
                o0 = __builtin_amdgcn_mfma_f32_16x16x32_bf16(af, w2[ks * 2 + 0], o0, 0, 0, 0);
                o1 = __builtin_amdgcn_mfma_f32_16x16x32_bf16(af, w2[ks * 2 + 1], o1, 0, 0, 0);
            }
            // O -> wave-private sO
            float* sOw = sO + wv * 512;
            const float* B2 = phase ? b2p : b2q;
            #pragma unroll
            for (int nt = 0; nt < 2; ++nt) {
                const int col = nt * 16 + l16;
                const float b2v = B2[col];
                const f32x4 av = nt ? o1 : o0;
                #pragma unroll
                for (int rg = 0; rg < 4; ++rg)
                    sOw[(quad * 4 + rg) * DD + col] = av[rg] + b2v;
            }
            // LDS fp32 RMW + bf16 publish (sys-store issued first)
            #pragma unroll
            for (int it = 0; it < 2; ++it) {
                const int slot = lane + it * 64;   // 128 float4 slots = 16 rows x 8
                const int lr = slot >> 3, seg = (slot & 7) * 4;
                const int pt_ = wv * 16 + lr;      // wave-private rows
                const float* po = &sOw[lr * DD + seg];
                float* pl = dstL + pt_ * SQ_STRIDE + seg;
                float4 o = *(const float4*)pl;
                o.x += dt * po[0]; o.y += dt * po[1];
                o.z += dt * po[2]; o.w += dt * po[3];
                st_sysb4(ebuf + ((size_t)(b * 64 + r) * 64 + pt_) * 64 + dso + seg, o);
                *(float4*)pl = o;
            }
        }
        // publish completion: wave-scoped drains, no block barrier
        __asm__ volatile("s_waitcnt vmcnt(0)" ::: "memory");
        if (lane == 0)
            __hip_atomic_store(flOw, (uint)(h + 1), __ATOMIC_RELAXED, __HIP_MEMORY_SCOPE_SYSTEM);
        __asm__ volatile("s_waitcnt lgkmcnt(0)" ::: "memory");
        if (lane == 0)
            __hip_atomic_store(&ldsF[wv], (uint)(h + 1), __ATOMIC_RELAXED, __HIP_MEMORY_SCOPE_WORKGROUP);
        if (phase) tp += dtmax; else tq += dtmax;
    }

    // ---- final state -> d_out (pt rows are wave-private: no barrier) ----
    {
        float* dst = out + (size_t)(b * NPTS + r * GRID_W + pt) * DIN;
        *(float4*)(dst + sg)          = *(const float4*)&sQ[pt * SQ_STRIDE + sg];
        *(float4*)(dst + sg + 4)      = *(const float4*)&sQ[pt * SQ_STRIDE + sg + 4];
        *(float4*)(dst + DD + sg)     = *(const float4*)&sP[pt * SQ_STRIDE + sg];
        *(float4*)(dst + DD + sg + 4) = *(const float4*)&sP[pt * SQ_STRIDE + sg + 4];
    }
}

// ---------------- fallback path (round-8-proven, global fp32 state) ----------------
__global__ __launch_bounds__(256, 2) void sympl_step(
    float* __restrict__ state, const float* __restrict__ tfinal,
    const char* __restrict__ ws,
    const float* __restrict__ B1, const float* __restrict__ B2,
    int phase, float tcur, float dtmax)
{
    __shared__ __align__(16) ushort sH[64 * SH_STRIDE];
    __shared__ __align__(16) float  sO[4 * 512];
    const int blk = blockIdx.x, tid = threadIdx.x;
    const int wv = tid >> 6, lane = tid & 63;
    const int l16 = lane & 15, quad = lane >> 4, q8 = quad * 8;
    const int b = blk >> 6, r = blk & 63;
    const int c = wv * 16 + l16;

    const float tf = tfinal[b];
    const float dt = fminf(fmaxf(tf - tcur, 0.0f), dtmax);
    if (dt <= 0.0f) return;

    const int srcoff = phase ? 0 : DD;
    const int dstoff = phase ? DD : 0;
    float* bb = state + (size_t)b * NPTS * DIN;
    const float* selfp = bb + (r * GRID_W + c) * DIN;
    const int rm = (r + 63) & 63, rp = (r + 1) & 63;
    const int cm = (c + 63) & 63, cp = (c + 1) & 63;
    short8 af0, af1, af2;
    {
        const float* ps = selfp + srcoff + q8;
        af0 = pack8(*(const float4*)ps, *(const float4*)(ps + 4));
    }
    {
        const float* p0 = bb + (rm * GRID_W + c) * DIN + srcoff + q8;
        const float* p1 = bb + (rp * GRID_W + c) * DIN + srcoff + q8;
        const float* p2 = bb + (r * GRID_W + cm) * DIN + srcoff + q8;
        const float* p3 = bb + (r * GRID_W + cp) * DIN + srcoff + q8;
        float4 a0 = *(const float4*)p0, a1 = *(const float4*)(p0 + 4);
        float4 b0 = *(const float4*)p1, b1v = *(const float4*)(p1 + 4);
        float4 c0 = *(const float4*)p2, c1 = *(const float4*)(p2 + 4);
        float4 d0 = *(const float4*)p3, d1 = *(const float4*)(p3 + 4);
        float4 m0, m1;
        m0.x = 0.25f * (a0.x + b0.x + c0.x + d0.x);
        m0.y = 0.25f * (a0.y + b0.y + c0.y + d0.y);
        m0.z = 0.25f * (a0.z + b0.z + c0.z + d0.z);
        m0.w = 0.25f * (a0.w + b0.w + c0.w + d0.w);
        m1.x = 0.25f * (a1.x + b1v.x + c1.x + d1.x);
        m1.y = 0.25f * (a1.y + b1v.y + c1.y + d1.y);
        m1.z = 0.25f * (a1.z + b1v.z + c1.z + d1.z);
        m1.w = 0.25f * (a1.w + b1v.w + c1.w + d1.w);
        af1 = pack8(m0, m1);
    }
    if (quad < 2) {
        const float* px = selfp + 2 * DD + q8;
        af2 = pack8(*(const float4*)px, *(const float4*)(px + 4));
    } else {
        af2 = (short8)(short)0;
    }
    const short8* F1 = (const short8*)(ws + (phase ? OFF_F1P : OFF_F1Q));
    const short8* F2 = (const short8*)(ws + (phase ? OFF_F2P : OFF_F2Q));
    short8 w2[8];
    #pragma unroll
    for (int i = 0; i < 8; ++i) w2[i] = F2[i * 64 + lane];
    Acc2 A = eval_F(af0, af1, af2, F1, w2, B1, sH, wv, lane, l16, quad, q8);
    float* sOw = sO + wv * 512;
    #pragma unroll
    for (int nt = 0; nt < 2; ++nt) {
        const int col = nt * 16 + l16;
        const float b2v = B2[col];
        const f32x4 av = nt ? A.a1 : A.a0;
        #pragma unroll
        for (int rg = 0; rg < 4; ++rg)
            sOw[(quad * 4 + rg) * DD + col] = av[rg] + b2v;
    }
    #pragma unroll
    for (int it = 0; it < 2; ++it) {
        const int slot = lane + it * 64;
        const int lr = slot >> 3, seg = (slot & 7) * 4;
        float* pd = bb + (r * GRID_W + wv * 16 + lr) * DIN + dstoff + seg;
        const float* po = &sOw[lr * DD + seg];
        float4 o = *(const float4*)pd;
        o.x += dt * po[0]; o.y += dt * po[1];
        o.z += dt * po[2]; o.w += dt * po[3];
        *(float4*)pd = o;
    }
}

extern "C" void kernel_launch(void* const* d_in, const int* in_sizes, int n_in,
                              void* d_out, int out_size, void* d_ws, size_t ws_size,
                              hipStream_t stream)
{
    const float* x   = (const float*)d_in[0];
    const float* tf  = (const float*)d_in[1];
    const float* W1q = (const float*)d_in[2];
    const float* b1q = (const float*)d_in[3];
    const float* W2q = (const float*)d_in[4];
    const float* b2q = (const float*)d_in[5];
    const float* W1p = (const float*)d_in[6];
    const float* b1p = (const float*)d_in[7];
    const float* W2p = (const float*)d_in[8];
    const float* b2p = (const float*)d_in[9];
    float* out = (float*)d_out;
    char* ws = (char*)d_ws;

    // d_out: [b][i][q(32) p(32) xi(16)] — xi + initial state
    hipMemcpyAsync(out, x, (size_t)BATCH * NPTS * DIN * sizeof(float),
                   hipMemcpyDeviceToDevice, stream);
    hipMemsetAsync(ws, 0, NBLK * 4 * 64, stream);      // per-wave step flags
    pack_weights<<<dim3(2), dim3(256), 0, stream>>>(W1q, W2q, W1p, W2p, ws);
    init_ebuf<<<dim3(NBLK), dim3(256), 0, stream>>>(x, ws);

    void* args[] = { (void*)&out, (void*)&tf, (void*)&ws,
                     (void*)&b1q, (void*)&b2q, (void*)&b1p, (void*)&b2p };
    hipError_t e = hipLaunchCooperativeKernel((const void*)sympl_coop,
                                              dim3(NBLK), dim3(256), args, 0, stream);
    if (e != hipSuccess) {
        // Fallback: 34 regular launches (kernel-boundary coherence).
        float tq = 0.0f, tp = 0.0f;
        for (int h = 0; h < NSTEP; ++h) {
            const int phase = h & 1;
            const float dtmax = phase ? 0.25f : ((h == 0) ? 0.125f : 0.25f);
            const float tcur  = phase ? tp : tq;
            sympl_step<<<dim3(NBLK), dim3(256), 0, stream>>>(
                out, tf, ws, phase ? b1p : b1q, phase ? b2p : b2q,
                phase, tcur, dtmax);
            if (phase) tp += dtmax; else tq += dtmax;
        }
    }
}